// Round 8
// baseline (414.238 us; speedup 1.0000x reference)
//
#include <hip/hip_runtime.h>
#include <hip/hip_bf16.h>

#define DFEAT 128
#define BETA 0.1f

typedef __attribute__((ext_vector_type(8))) short bf16x8;
typedef __attribute__((ext_vector_type(4))) float f32x4;

// ---------------- bf16 helpers ----------------
__device__ inline unsigned bf16rne(float f) {
    unsigned u = __float_as_uint(f);
    return (u + 0x7fffu + ((u >> 16) & 1u)) >> 16;
}
__device__ inline void accum8(float* a, int4 v, float w) {
    a[0] += __int_as_float(v.x << 16) * w;
    a[1] += __int_as_float(v.x & 0xffff0000) * w;
    a[2] += __int_as_float(v.y << 16) * w;
    a[3] += __int_as_float(v.y & 0xffff0000) * w;
    a[4] += __int_as_float(v.z << 16) * w;
    a[5] += __int_as_float(v.z & 0xffff0000) * w;
    a[6] += __int_as_float(v.w << 16) * w;
    a[7] += __int_as_float(v.w & 0xffff0000) * w;
}

// asm 16B global load: guaranteed issued, not serialized by the compiler
__device__ inline int4 gload16(const int4* p) {
    int4 v;
    asm volatile("global_load_dwordx4 %0, %1, off" : "=v"(v) : "v"(p));
    return v;
}

// ---------------- in-degree count ----------------
__global__ void count_indeg(const int* __restrict__ dst, int* __restrict__ indeg, int E) {
    int e = blockIdx.x * blockDim.x + threadIdx.x;
    if (e < E) atomicAdd(&indeg[dst[e]], 1);
}

// ---------------- prefix scan (3-kernel) ----------------
__global__ void block_sums(const int* __restrict__ indeg, int* __restrict__ bsum, int N) {
    __shared__ int sh[256];
    int i = blockIdx.x * 256 + threadIdx.x;
    sh[threadIdx.x] = (i < N) ? indeg[i] : 0;
    __syncthreads();
    for (int s = 128; s > 0; s >>= 1) {
        if (threadIdx.x < s) sh[threadIdx.x] += sh[threadIdx.x + s];
        __syncthreads();
    }
    if (threadIdx.x == 0) bsum[blockIdx.x] = sh[0];
}

__global__ void scan_bsum(int* __restrict__ bsum, int nb) {
    __shared__ int sh[256];
    __shared__ int carry;
    if (threadIdx.x == 0) carry = 0;
    __syncthreads();
    for (int base = 0; base < nb; base += 256) {
        int i = base + threadIdx.x;
        int v = (i < nb) ? bsum[i] : 0;
        sh[threadIdx.x] = v;
        __syncthreads();
        for (int s = 1; s < 256; s <<= 1) {
            int t = (threadIdx.x >= s) ? sh[threadIdx.x - s] : 0;
            __syncthreads();
            sh[threadIdx.x] += t;
            __syncthreads();
        }
        int incl = sh[threadIdx.x];
        if (i < nb) bsum[i] = incl - v + carry;
        int total = sh[255];
        __syncthreads();
        if (threadIdx.x == 0) carry += total;
        __syncthreads();
    }
}

// scan_final + fused norm computation
__global__ void scan_final(const int* __restrict__ indeg, const int* __restrict__ bsum,
                           int* __restrict__ rowptr, int* __restrict__ cursor,
                           float* __restrict__ norm, int N) {
    __shared__ int sh[256];
    int i = blockIdx.x * 256 + threadIdx.x;
    int v = (i < N) ? indeg[i] : 0;
    sh[threadIdx.x] = v;
    __syncthreads();
    for (int s = 1; s < 256; s <<= 1) {
        int t = (threadIdx.x >= s) ? sh[threadIdx.x - s] : 0;
        __syncthreads();
        sh[threadIdx.x] += t;
        __syncthreads();
    }
    int excl = sh[threadIdx.x] - v + bsum[blockIdx.x];
    if (i < N) {
        rowptr[i] = excl; cursor[i] = excl;
        norm[i] = rsqrtf((float)(v > 1 ? v : 1));
    }
    if (i == N - 1) rowptr[N] = excl + v;
}

// ------- CSR perm: 4B scattered write only -------
__global__ void fill_perm(const int* __restrict__ dst, int* __restrict__ cursor,
                          int* __restrict__ perm, int E) {
    int e = blockIdx.x * blockDim.x + threadIdx.x;
    if (e >= E) return;
    int p = atomicAdd(&cursor[dst[e]], 1);
    perm[p] = e;
}

// ------- epack materialization: sequential writes, small random reads -------
__global__ void build_epack(const int* __restrict__ perm, const int* __restrict__ src,
                            const float* __restrict__ efac, int2* __restrict__ epack, int E) {
    int p = blockIdx.x * blockDim.x + threadIdx.x;
    if (p >= E) return;
    int e = perm[p];
    float w0 = efac[e] * (1.0f - BETA);
    float w1 = efac[(size_t)E + e] * (1.0f - BETA);
    unsigned pw = bf16rne(w0) | (bf16rne(w1) << 16);
    epack[p] = make_int2(src[e], (int)pw);
}

// ------- prep: hn0b = bf16(features*norm), f0s = bf16(features*0.1) -------
__global__ void prep2(const float* __restrict__ feat, const float* __restrict__ norm,
                      unsigned* __restrict__ hnb2, unsigned* __restrict__ f0s2, int N) {
    int i = blockIdx.x * blockDim.x + threadIdx.x;
    if (i >= N * (DFEAT / 4)) return;
    int n = i >> 5;
    float nm = norm[n];
    float4 v = ((const float4*)feat)[i];
    unsigned a0 = bf16rne(v.x * nm) | (bf16rne(v.y * nm) << 16);
    unsigned a1 = bf16rne(v.z * nm) | (bf16rne(v.w * nm) << 16);
    unsigned b0 = bf16rne(v.x * BETA) | (bf16rne(v.y * BETA) << 16);
    unsigned b1 = bf16rne(v.z * BETA) | (bf16rne(v.w * BETA) << 16);
    hnb2[2 * i] = a0; hnb2[2 * i + 1] = a1;
    f0s2[2 * i] = b0; f0s2[2 * i + 1] = b1;
}

// ------- W conversion: wt[g][col][k] = bf16(W[g][k][col]) -------
__global__ void wconv(const float* __restrict__ W, short* __restrict__ wt, int total) {
    int i = blockIdx.x * blockDim.x + threadIdx.x;
    if (i >= total) return;
    int g = i >> 14;
    int r = i & 16383;
    int col = r >> 7, k = r & 127;
    wt[(size_t)g * 16384 + col * 128 + k] =
        (short)bf16rne(W[(size_t)g * 16384 + (size_t)k * 128 + col]);
}

// -------- fused dual-graph gather hop (32 lanes/node: grp=lane>>4, c=lane&15) ----
// 8 asm loads issued back-to-back, one vmcnt(0) fence + sched_barrier (rule #18)
__global__ __launch_bounds__(256) void gather_fused(
        const int4* __restrict__ hn0, const int4* __restrict__ hn1,
        const int4* __restrict__ f0s, const float* __restrict__ norm,
        const int* __restrict__ rowptr, const int2* __restrict__ ep,
        int4* __restrict__ out0, int4* __restrict__ out1,
        int N, int last) {
    int tid = blockIdx.x * blockDim.x + threadIdx.x;
    int n = tid >> 5;
    if (n >= N) return;
    int lane = tid & 31;
    int grp = lane >> 4;
    int c = lane & 15;
    const int4* hn = grp ? hn1 : hn0;

    int beg = rowptr[n], end = rowptr[n + 1];
    int4 f = f0s[(size_t)n * 16 + c];

    float acc[8] = {0, 0, 0, 0, 0, 0, 0, 0};
    int i = beg;
    int nfull = (end - beg) >> 3;
    for (int blk = 0; blk < nfull; blk++, i += 8) {
        int2 m0 = ep[i],     m1 = ep[i + 1], m2 = ep[i + 2], m3 = ep[i + 3];
        int2 m4 = ep[i + 4], m5 = ep[i + 5], m6 = ep[i + 6], m7 = ep[i + 7];
        int4 v0 = gload16(hn + ((size_t)m0.x << 4) + c);
        int4 v1 = gload16(hn + ((size_t)m1.x << 4) + c);
        int4 v2 = gload16(hn + ((size_t)m2.x << 4) + c);
        int4 v3 = gload16(hn + ((size_t)m3.x << 4) + c);
        int4 v4 = gload16(hn + ((size_t)m4.x << 4) + c);
        int4 v5 = gload16(hn + ((size_t)m5.x << 4) + c);
        int4 v6 = gload16(hn + ((size_t)m6.x << 4) + c);
        int4 v7 = gload16(hn + ((size_t)m7.x << 4) + c);
        asm volatile("s_waitcnt vmcnt(0)" ::: "memory");
        __builtin_amdgcn_sched_barrier(0);
        accum8(acc, v0, __int_as_float(grp ? (m0.y & 0xffff0000) : (m0.y << 16)));
        accum8(acc, v1, __int_as_float(grp ? (m1.y & 0xffff0000) : (m1.y << 16)));
        accum8(acc, v2, __int_as_float(grp ? (m2.y & 0xffff0000) : (m2.y << 16)));
        accum8(acc, v3, __int_as_float(grp ? (m3.y & 0xffff0000) : (m3.y << 16)));
        accum8(acc, v4, __int_as_float(grp ? (m4.y & 0xffff0000) : (m4.y << 16)));
        accum8(acc, v5, __int_as_float(grp ? (m5.y & 0xffff0000) : (m5.y << 16)));
        accum8(acc, v6, __int_as_float(grp ? (m6.y & 0xffff0000) : (m6.y << 16)));
        accum8(acc, v7, __int_as_float(grp ? (m7.y & 0xffff0000) : (m7.y << 16)));
    }
    for (; i < end; ++i) {
        int2 m = ep[i];
        float w = __int_as_float(grp ? (m.y & 0xffff0000) : (m.y << 16));
        int4 v = hn[(size_t)m.x * 16 + c];
        accum8(acc, v, w);
    }

    float r[8];
    r[0] = acc[0] + __int_as_float(f.x << 16);
    r[1] = acc[1] + __int_as_float(f.x & 0xffff0000);
    r[2] = acc[2] + __int_as_float(f.y << 16);
    r[3] = acc[3] + __int_as_float(f.y & 0xffff0000);
    r[4] = acc[4] + __int_as_float(f.z << 16);
    r[5] = acc[5] + __int_as_float(f.z & 0xffff0000);
    r[6] = acc[6] + __int_as_float(f.w << 16);
    r[7] = acc[7] + __int_as_float(f.w & 0xffff0000);

    if (!last) {
        float nm = norm[n];
        #pragma unroll
        for (int j = 0; j < 8; j++) r[j] *= nm;
    }
    int4 o;
    o.x = (int)(bf16rne(r[0]) | (bf16rne(r[1]) << 16));
    o.y = (int)(bf16rne(r[2]) | (bf16rne(r[3]) << 16));
    o.z = (int)(bf16rne(r[4]) | (bf16rne(r[5]) << 16));
    o.w = (int)(bf16rne(r[6]) | (bf16rne(r[7]) << 16));
    (grp ? out1 : out0)[(size_t)n * 16 + c] = o;
}

// ---------------- MFMA epilogue GEMM ----------------
// out[:, g*128:(g+1)*128] = relu(Hb @ W + b), Hb bf16 [N][128], wt = W^T bf16 [128col][128k]
#define WT_LD 136   // padded col stride (shorts): 272B -> 2-way bank alias (free)
__global__ __launch_bounds__(256) void gemm_mfma(
        const int4* __restrict__ hb, const short* __restrict__ wt,
        const float* __restrict__ bias, float* __restrict__ out,
        int N, int G, int g) {
    __shared__ short Wl[128 * WT_LD];   // 34.8 KB

    int tid = threadIdx.x;
    for (int i = tid; i < 2048; i += 256) {          // 128x128 shorts = 2048 int4
        int col = i >> 4, k8 = i & 15;
        *(int4*)(Wl + col * WT_LD + k8 * 8) = ((const int4*)wt)[i];
    }
    __syncthreads();

    int wave = tid >> 6, lane = tid & 63;
    int row0 = blockIdx.x * 64 + wave * 16;
    int lrow = lane & 15, lk = lane >> 4;            // A row / k-block

    int arow = row0 + lrow; if (arow >= N) arow = N - 1;   // clamp; stores guarded
    const short* aptr = (const short*)hb + (size_t)arow * DFEAT + lk * 8;

    f32x4 acc[8];
    #pragma unroll
    for (int t = 0; t < 8; t++) acc[t] = (f32x4){0.f, 0.f, 0.f, 0.f};

    #pragma unroll
    for (int ki = 0; ki < 4; ki++) {
        bf16x8 a = *(const bf16x8*)(aptr + ki * 32);
        #pragma unroll
        for (int t = 0; t < 8; t++) {
            int col = t * 16 + lrow;
            bf16x8 bf = *(const bf16x8*)(Wl + col * WT_LD + ki * 32 + lk * 8);
            acc[t] = __builtin_amdgcn_mfma_f32_16x16x32_bf16(a, bf, acc[t], 0, 0, 0);
        }
    }

    // D layout: col = lane&15 (+16t), row = (lane>>4)*4 + j (+row0)
    #pragma unroll
    for (int t = 0; t < 8; t++) {
        int col = t * 16 + lrow;
        float bv = bias[col];
        #pragma unroll
        for (int j = 0; j < 4; j++) {
            int row = row0 + lk * 4 + j;
            if (row < N)
                out[(size_t)row * (G * DFEAT) + g * DFEAT + col] = fmaxf(acc[t][j] + bv, 0.0f);
        }
    }
}

static inline size_t align256(size_t x) { return (x + 255) & ~(size_t)255; }

extern "C" void kernel_launch(void* const* d_in, const int* in_sizes, int n_in,
                              void* d_out, int out_size, void* d_ws, size_t ws_size,
                              hipStream_t stream) {
    const float* features = (const float*)d_in[0];
    const int*   src      = (const int*)d_in[1];
    const int*   dst      = (const int*)d_in[2];
    const float* efac     = (const float*)d_in[3];
    const float* W        = (const float*)d_in[4];
    const float* b        = (const float*)d_in[5];
    float* out = (float*)d_out;

    int N = in_sizes[0] / DFEAT;
    int E = in_sizes[1];
    int G = in_sizes[3] / E;   // == 2
    int nb = (N + 255) / 256;

    size_t bf16Bytes = (size_t)N * DFEAT * 2;                // 12.8 MB

    char* p = (char*)d_ws;
    int4*  hn0b   = (int4*)p;  p += align256(bf16Bytes);
    int4*  f0s    = (int4*)p;  p += align256(bf16Bytes);
    int4*  A0     = (int4*)p;  p += align256(bf16Bytes);
    int4*  A1     = (int4*)p;  p += align256(bf16Bytes);
    int4*  B0     = (int4*)p;  p += align256(bf16Bytes);
    int4*  B1     = (int4*)p;  p += align256(bf16Bytes);
    int*   indeg  = (int*)p;   p += align256((size_t)N * 4);
    float* norm   = (float*)p; p += align256((size_t)N * 4);
    int*   rowptr = (int*)p;   p += align256((size_t)(N + 1) * 4);
    int*   cursor = (int*)p;   p += align256((size_t)N * 4);
    int*   bsum   = (int*)p;   p += align256((size_t)nb * 4);
    int2*  epack  = (int2*)p;  p += align256((size_t)E * 8);
    short* wt     = (short*)p; p += align256((size_t)G * DFEAT * DFEAT * 2);
    int*   perm   = (int*)A0;  // alias: dead before hop1 writes A0

    // ---- build norm + CSR (shared across graphs) ----
    hipMemsetAsync(indeg, 0, (size_t)N * 4, stream);
    count_indeg<<<(E + 255) / 256, 256, 0, stream>>>(dst, indeg, E);
    block_sums<<<nb, 256, 0, stream>>>(indeg, bsum, N);
    scan_bsum<<<1, 256, 0, stream>>>(bsum, nb);
    scan_final<<<nb, 256, 0, stream>>>(indeg, bsum, rowptr, cursor, norm, N);
    fill_perm<<<(E + 255) / 256, 256, 0, stream>>>(dst, cursor, perm, E);
    build_epack<<<(E + 255) / 256, 256, 0, stream>>>(perm, src, efac, epack, E);

    int prepBlocks   = (N * (DFEAT / 4) + 255) / 256;
    int gatherBlocks = (N * 32 + 255) / 256;
    int gemmBlocks   = (N + 63) / 64;
    int wtotal       = G * DFEAT * DFEAT;

    prep2<<<prepBlocks, 256, 0, stream>>>(features, norm, (unsigned*)hn0b, (unsigned*)f0s, N);
    wconv<<<(wtotal + 255) / 256, 256, 0, stream>>>(W, wt, wtotal);

    // fused hops: (hn0b,hn0b) -> (A0,A1) -> (B0,B1) -> (A0,A1) -> (B0,B1)[last]
    gather_fused<<<gatherBlocks, 256, 0, stream>>>(hn0b, hn0b, f0s, norm, rowptr, epack, A0, A1, N, 0);
    gather_fused<<<gatherBlocks, 256, 0, stream>>>(A0, A1, f0s, norm, rowptr, epack, B0, B1, N, 0);
    gather_fused<<<gatherBlocks, 256, 0, stream>>>(B0, B1, f0s, norm, rowptr, epack, A0, A1, N, 0);
    gather_fused<<<gatherBlocks, 256, 0, stream>>>(A0, A1, f0s, norm, rowptr, epack, B0, B1, N, 1);

    gemm_mfma<<<gemmBlocks, 256, 0, stream>>>(B0, wt,          b,         out, N, G, 0);
    gemm_mfma<<<gemmBlocks, 256, 0, stream>>>(B1, wt + 16384,  b + DFEAT, out, N, G, 1);
}